// Round 7
// baseline (416.463 us; speedup 1.0000x reference)
//
#include <hip/hip_runtime.h>

// ---------------------------------------------------------------------------
// EMOGI ChebConv-K2 x3 : N=100000 nodes, E=800000 edges, dims 58->300->100->1
// bf16 MFMA edition + MLP-unrolled gathers + LDS-staged coalesced C-writes.
//   CSR by dst (count/scan/fill) -> gathers, no float atomics.
//   xb  [NR][128] bf16 = [x | p1 | 0]       (p1 filled by gather58)
//   h1b [NR][320] bf16 = relu([x|p1]@[W10;W11] + b1), K-pad cols zeroed
//   mm2: ga2b[NR][208] = h1b @ [W21|pad|W20|pad]^T (cols 0..99 g2, 104..203 a2)
//   gather_l2: p2 = prop(g2); h2 = relu(a2+p2+b2) in-reg; a3,g3 = h2@W3 dots
//   gather1: out = a3 + prop(g3)
// R6 lesson: with col-tile as the OUTER loop, only the A-fragments persist
// across it and the compiler SINKS (re-materializes) their loads inside the
// loop -> 13x redundant strided loads, 79us, MfmaUtil 6%, VGPR stuck at 68.
// launch_bounds can't fix a scheduler heuristic. Fix: K-outer / col-inner
// loop nest, so the persistent state is the per-column ACCUMULATORS, which
// dataflow forces register-resident; each A-frag is loaded once and consumed
// immediately.
// ---------------------------------------------------------------------------

typedef short bf16x8 __attribute__((ext_vector_type(8)));
typedef float f32x4 __attribute__((ext_vector_type(4)));

__device__ __forceinline__ unsigned f2bf(float f) {  // RNE fp32->bf16 bits
  unsigned u = __float_as_uint(f);
  u += 0x7fff + ((u >> 16) & 1);
  return u >> 16;
}
__device__ __forceinline__ float bf2f(unsigned s) {
  return __uint_as_float(s << 16);
}

// ---------------- CSR build ----------------
__global__ void k_count(const int* __restrict__ src, const int* __restrict__ dst,
                        unsigned* __restrict__ deg, unsigned* __restrict__ cnt, int E) {
  int i = blockIdx.x * blockDim.x + threadIdx.x;
  if (i < E) {
    atomicAdd(&deg[src[i]], 1u);
    atomicAdd(&cnt[dst[i]], 1u);
  }
}

__global__ void k_dinv(const unsigned* __restrict__ deg, float* __restrict__ dinv, int N) {
  int i = blockIdx.x * blockDim.x + threadIdx.x;
  if (i < N) {
    unsigned d = deg[i];
    dinv[i] = d ? rsqrtf((float)d) : 0.0f;
  }
}

__global__ __launch_bounds__(256) void k_scan1(const unsigned* __restrict__ cnt,
                                               unsigned* __restrict__ btot, int N) {
  __shared__ unsigned s[256];
  int b = blockIdx.x, t = threadIdx.x;
  int base = b * 1024;
  unsigned sum = 0;
  for (int i = t; i < 1024; i += 256) {
    int idx = base + i;
    sum += (idx < N) ? cnt[idx] : 0u;
  }
  s[t] = sum;
  __syncthreads();
  for (int off = 128; off > 0; off >>= 1) {
    if (t < off) s[t] += s[t + off];
    __syncthreads();
  }
  if (t == 0) btot[b] = s[0];
}

__global__ __launch_bounds__(256) void k_scan2(unsigned* __restrict__ btot,
                                               unsigned* __restrict__ rowstart,
                                               int NB, int N, int E) {
  __shared__ unsigned s[256];
  int t = threadIdx.x;
  s[t] = (t < NB) ? btot[t] : 0u;
  __syncthreads();
  if (t == 0) {
    unsigned acc = 0;
    for (int i = 0; i < NB; i++) { unsigned v = s[i]; s[i] = acc; acc += v; }
  }
  __syncthreads();
  if (t < NB) btot[t] = s[t];
  if (t == 0) rowstart[N] = (unsigned)E;
}

__global__ __launch_bounds__(256) void k_scan3(const unsigned* __restrict__ cnt,
                                               const unsigned* __restrict__ btot,
                                               unsigned* __restrict__ rowstart,
                                               unsigned* __restrict__ cursor, int N) {
  __shared__ unsigned ssum[256];
  int b = blockIdx.x, t = threadIdx.x;
  int base = b * 1024 + t * 4;
  unsigned v0 = 0, v1 = 0, v2 = 0, v3 = 0;
  if (base + 0 < N) v0 = cnt[base + 0];
  if (base + 1 < N) v1 = cnt[base + 1];
  if (base + 2 < N) v2 = cnt[base + 2];
  if (base + 3 < N) v3 = cnt[base + 3];
  ssum[t] = v0 + v1 + v2 + v3;
  __syncthreads();
  for (int off = 1; off < 256; off <<= 1) {
    unsigned add = (t >= off) ? ssum[t - off] : 0u;
    __syncthreads();
    ssum[t] += add;
    __syncthreads();
  }
  unsigned texcl = ((t == 0) ? 0u : ssum[t - 1]) + btot[b];
  unsigned r0 = texcl, r1 = r0 + v0, r2 = r1 + v1, r3 = r2 + v2;
  if (base + 0 < N) { rowstart[base + 0] = r0; cursor[base + 0] = r0; }
  if (base + 1 < N) { rowstart[base + 1] = r1; cursor[base + 1] = r1; }
  if (base + 2 < N) { rowstart[base + 2] = r2; cursor[base + 2] = r2; }
  if (base + 3 < N) { rowstart[base + 3] = r3; cursor[base + 3] = r3; }
}

__global__ void k_fill(const int* __restrict__ src, const int* __restrict__ dst,
                       const float* __restrict__ dinv, unsigned* __restrict__ cursor,
                       int2* __restrict__ er, int E) {
  int e = blockIdx.x * blockDim.x + threadIdx.x;
  if (e >= E) return;
  int s = src[e], d = dst[e];
  unsigned pos = atomicAdd(&cursor[d], 1u);
  er[pos] = make_int2(s, __float_as_int(dinv[s]));
}

// ---------------- prep kernels ----------------
__global__ void k_prep_xb(const float* __restrict__ x, unsigned short* __restrict__ xb, int N) {
  int idx = blockIdx.x * blockDim.x + threadIdx.x;
  int n = idx >> 6, p = idx & 63;
  if (n >= N) return;
  int c = p * 2;
  if (c < 58) {
    unsigned lo = f2bf(x[(size_t)n * 58 + c]);
    unsigned hi = f2bf(x[(size_t)n * 58 + c + 1]);
    *(unsigned*)(xb + (size_t)n * 128 + c) = lo | (hi << 16);
  } else if (c >= 116) {
    *(unsigned*)(xb + (size_t)n * 128 + c) = 0;
  }
}

__global__ void k_prep_w1(const float* __restrict__ W1, unsigned short* __restrict__ Wt1) {
  int idx = blockIdx.x * blockDim.x + threadIdx.x;
  int j = idx >> 6, p = idx & 63;
  if (j >= 304) return;
  int k = p * 2;
  unsigned v[2];
#pragma unroll
  for (int q = 0; q < 2; q++) {
    int kk = k + q;
    float f = 0.0f;
    if (j < 300) {
      if (kk < 58) f = W1[kk * 300 + j];
      else if (kk < 116) f = W1[17400 + (kk - 58) * 300 + j];
    }
    v[q] = f2bf(f);
  }
  *(unsigned*)(Wt1 + j * 128 + k) = v[0] | (v[1] << 16);
}

__global__ void k_prep_w2(const float* __restrict__ W2, unsigned short* __restrict__ Wt2) {
  int idx = blockIdx.x * blockDim.x + threadIdx.x;
  int r = idx / 160, p = idx % 160;
  if (r >= 208) return;
  int k = p * 2;
  unsigned v[2];
#pragma unroll
  for (int q = 0; q < 2; q++) {
    int kk = k + q;
    float f = 0.0f;
    if (kk < 300) {
      if (r < 100) f = W2[30000 + kk * 100 + r];
      else if (r >= 104 && r < 204) f = W2[kk * 100 + (r - 104)];
    }
    v[q] = f2bf(f);
  }
  *(unsigned*)(Wt2 + r * 320 + k) = v[0] | (v[1] << 16);
}

// ---------------- gathers (x4 MLP-unrolled) ----------------
__global__ __launch_bounds__(256) void k_gather58(
    const unsigned* __restrict__ rowstart, const int2* __restrict__ er,
    const float* __restrict__ dinv, unsigned short* __restrict__ xb, int N) {
  int wid = (blockIdx.x * blockDim.x + threadIdx.x) >> 6;
  if (wid >= N) return;
  int lane = threadIdx.x & 63;
  int c0 = lane * 2;
  if (c0 >= 58) return;
  unsigned s0 = rowstart[wid], s1 = rowstart[wid + 1];
  float a0 = 0.f, a1 = 0.f, b0 = 0.f, b1 = 0.f;
  float c0a = 0.f, c1a = 0.f, d0 = 0.f, d1 = 0.f;
  unsigned e = s0;
  for (; e + 4 <= s1; e += 4) {
    int2 r0 = er[e], r1 = er[e + 1], r2 = er[e + 2], r3 = er[e + 3];
    unsigned v0 = *(const unsigned*)(xb + (size_t)r0.x * 128 + c0);
    unsigned v1 = *(const unsigned*)(xb + (size_t)r1.x * 128 + c0);
    unsigned v2 = *(const unsigned*)(xb + (size_t)r2.x * 128 + c0);
    unsigned v3 = *(const unsigned*)(xb + (size_t)r3.x * 128 + c0);
    float w0 = __int_as_float(r0.y), w1 = __int_as_float(r1.y);
    float w2 = __int_as_float(r2.y), w3 = __int_as_float(r3.y);
    a0 += w0 * bf2f(v0 & 0xffffu); a1 += w0 * bf2f(v0 >> 16);
    b0 += w1 * bf2f(v1 & 0xffffu); b1 += w1 * bf2f(v1 >> 16);
    c0a += w2 * bf2f(v2 & 0xffffu); c1a += w2 * bf2f(v2 >> 16);
    d0 += w3 * bf2f(v3 & 0xffffu); d1 += w3 * bf2f(v3 >> 16);
  }
  for (; e < s1; ++e) {
    int2 r = er[e];
    float w = __int_as_float(r.y);
    unsigned v = *(const unsigned*)(xb + (size_t)r.x * 128 + c0);
    a0 += w * bf2f(v & 0xffffu); a1 += w * bf2f(v >> 16);
  }
  float dd = -dinv[wid];
  float p0 = dd * ((a0 + b0) + (c0a + d0));
  float p1 = dd * ((a1 + b1) + (c1a + d1));
  *(unsigned*)(xb + (size_t)wid * 128 + 58 + c0) = f2bf(p0) | (f2bf(p1) << 16);
}

// layer2 tail fused: p2 = prop(g2); h2 = relu(a2+p2+b2); a3,g3 = h2@W30/W31
// ga2b row: cols 0..99 = g2, 104..203 = a2 (stride 208)
__global__ __launch_bounds__(256) void k_gather_l2(
    const unsigned* __restrict__ rowstart, const int2* __restrict__ er,
    const float* __restrict__ dinv, const unsigned short* __restrict__ ga2b,
    const float* __restrict__ b2, const float* __restrict__ W30,
    const float* __restrict__ W31, const float* __restrict__ b3,
    float* __restrict__ a3, float* __restrict__ g3, int N) {
  int wid = (blockIdx.x * blockDim.x + threadIdx.x) >> 6;
  if (wid >= N) return;
  int lane = threadIdx.x & 63;
  int c0 = lane * 2;
  bool act = c0 < 100;
  unsigned s0 = rowstart[wid], s1 = rowstart[wid + 1];
  float aa = 0.f, gg = 0.f;
  if (act) {
    float a0 = 0.f, a1 = 0.f, b0 = 0.f, b1 = 0.f;
    float c0a = 0.f, c1a = 0.f, d0 = 0.f, d1 = 0.f;
    unsigned e = s0;
    for (; e + 4 <= s1; e += 4) {
      int2 r0 = er[e], r1 = er[e + 1], r2 = er[e + 2], r3 = er[e + 3];
      unsigned v0 = *(const unsigned*)(ga2b + (size_t)r0.x * 208 + c0);
      unsigned v1 = *(const unsigned*)(ga2b + (size_t)r1.x * 208 + c0);
      unsigned v2 = *(const unsigned*)(ga2b + (size_t)r2.x * 208 + c0);
      unsigned v3 = *(const unsigned*)(ga2b + (size_t)r3.x * 208 + c0);
      float w0 = __int_as_float(r0.y), w1 = __int_as_float(r1.y);
      float w2 = __int_as_float(r2.y), w3 = __int_as_float(r3.y);
      a0 += w0 * bf2f(v0 & 0xffffu); a1 += w0 * bf2f(v0 >> 16);
      b0 += w1 * bf2f(v1 & 0xffffu); b1 += w1 * bf2f(v1 >> 16);
      c0a += w2 * bf2f(v2 & 0xffffu); c1a += w2 * bf2f(v2 >> 16);
      d0 += w3 * bf2f(v3 & 0xffffu); d1 += w3 * bf2f(v3 >> 16);
    }
    for (; e < s1; ++e) {
      int2 r = er[e];
      float w = __int_as_float(r.y);
      unsigned v = *(const unsigned*)(ga2b + (size_t)r.x * 208 + c0);
      a0 += w * bf2f(v & 0xffffu); a1 += w * bf2f(v >> 16);
    }
    float dd = -dinv[wid];
    float p0 = dd * ((a0 + b0) + (c0a + d0));
    float p1 = dd * ((a1 + b1) + (c1a + d1));
    unsigned av = *(const unsigned*)(ga2b + (size_t)wid * 208 + 104 + c0);
    float h0 = fmaxf(bf2f(av & 0xffffu) + p0 + b2[c0], 0.f);
    float h1 = fmaxf(bf2f(av >> 16) + p1 + b2[c0 + 1], 0.f);
    aa = h0 * W30[c0] + h1 * W30[c0 + 1];
    gg = h0 * W31[c0] + h1 * W31[c0 + 1];
  }
#pragma unroll
  for (int off = 32; off > 0; off >>= 1) {
    aa += __shfl_xor(aa, off);
    gg += __shfl_xor(gg, off);
  }
  if (lane == 0) {
    a3[wid] = aa + b3[0];
    g3[wid] = gg;
  }
}

__global__ void k_gather1(const unsigned* __restrict__ rowstart, const int2* __restrict__ er,
                          const float* __restrict__ dinv, const float* __restrict__ g3,
                          const float* __restrict__ a3, float* __restrict__ out, int N) {
  int n = blockIdx.x * blockDim.x + threadIdx.x;
  if (n >= N) return;
  unsigned s0 = rowstart[n], s1 = rowstart[n + 1];
  float a = 0.f, b = 0.f, c = 0.f, d = 0.f;
  unsigned e = s0;
  for (; e + 4 <= s1; e += 4) {
    int2 r0 = er[e], r1 = er[e + 1], r2 = er[e + 2], r3 = er[e + 3];
    float g0 = g3[r0.x], g1 = g3[r1.x], g2v = g3[r2.x], g3v = g3[r3.x];
    a += __int_as_float(r0.y) * g0;
    b += __int_as_float(r1.y) * g1;
    c += __int_as_float(r2.y) * g2v;
    d += __int_as_float(r3.y) * g3v;
  }
  for (; e < s1; ++e) {
    int2 r = er[e];
    a += __int_as_float(r.y) * g3[r.x];
  }
  out[n] = a3[n] - dinv[n] * ((a + b) + (c + d));
}

// ---------------- MFMA matmuls (K-outer, acc-resident; LDS-staged C) --------
// h1b = relu(xb @ Wt1^T + b1). 4 waves x 32 rows, K=128. Two 160-col halves;
// per half: s-outer loop loads A once, j-inner accumulates into 20 f32x4.
__global__ __launch_bounds__(256, 4) void k_mm1_mfma(
    const unsigned short* __restrict__ xb, const unsigned short* __restrict__ Wt1,
    const float* __restrict__ b1, unsigned short* __restrict__ h1b) {
  __shared__ unsigned short tile[4][32][160];  // 40 KB
  int wv = threadIdx.x >> 6, lane = threadIdx.x & 63;
  int rbase = blockIdx.x * 128 + wv * 32;
  int lr = lane & 15, lk = (lane >> 4) * 8;
#pragma unroll
  for (int half = 0; half < 2; half++) {
    const int NJ = half ? 9 : 10;
    int c0 = half * 160 + lr;
    f32x4 acc0[10], acc1[10];
#pragma unroll
    for (int j = 0; j < 10; j++) {
      acc0[j] = (f32x4){0.f, 0.f, 0.f, 0.f};
      acc1[j] = (f32x4){0.f, 0.f, 0.f, 0.f};
    }
#pragma unroll
    for (int s = 0; s < 4; s++) {
      bf16x8 a0 = *(const bf16x8*)(xb + (size_t)(rbase + lr) * 128 + s * 32 + lk);
      bf16x8 a1 = *(const bf16x8*)(xb + (size_t)(rbase + 16 + lr) * 128 + s * 32 + lk);
#pragma unroll
      for (int j = 0; j < NJ; j++) {
        bf16x8 b = *(const bf16x8*)(Wt1 + (size_t)(c0 + j * 16) * 128 + s * 32 + lk);
        acc0[j] = __builtin_amdgcn_mfma_f32_16x16x32_bf16(a0, b, acc0[j], 0, 0, 0);
        acc1[j] = __builtin_amdgcn_mfma_f32_16x16x32_bf16(a1, b, acc1[j], 0, 0, 0);
      }
    }
    int r0 = (lane >> 4) * 4;
#pragma unroll
    for (int j = 0; j < NJ; j++) {
      int c = half * 160 + j * 16 + lr;
      float bias = (c < 300) ? b1[c] : 0.0f;
      int lc = j * 16 + lr;
#pragma unroll
      for (int i = 0; i < 4; i++) {
        unsigned short v0 = (c < 300) ? (unsigned short)f2bf(fmaxf(acc0[j][i] + bias, 0.f)) : 0;
        unsigned short v1 = (c < 300) ? (unsigned short)f2bf(fmaxf(acc1[j][i] + bias, 0.f)) : 0;
        tile[wv][r0 + i][lc] = v0;
        tile[wv][r0 + 16 + i][lc] = v1;
      }
    }
    if (half == 1) {  // zero K-pad cols 304..319 (local 144..159)
      for (int idx = lane; idx < 32 * 16; idx += 64)
        tile[wv][idx >> 4][144 + (idx & 15)] = 0;
    }
    // copy wave tile: 32 rows x 320 B at global row stride 640 B
    for (int idx = lane; idx < 32 * 20; idx += 64) {
      int row = idx / 20, q = idx % 20;
      *(uint4*)(h1b + (size_t)(rbase + row) * 320 + half * 160 + q * 8) =
          *(const uint4*)&tile[wv][row][q * 8];
    }
  }
}

// ga2b = h1b @ Wt2^T. K=320 (10 s-steps), 13 col-tiles accumulated in
// registers (26 f32x4 = 104 VGPR); A loaded once per s. LDS 52KB -> 3 blk/CU.
__global__ __launch_bounds__(256, 3) void k_mm2_mfma(
    const unsigned short* __restrict__ h1b, const unsigned short* __restrict__ Wt2,
    unsigned short* __restrict__ ga2b) {
  __shared__ unsigned short tile[4][32][208];  // 52 KB
  int wv = threadIdx.x >> 6, lane = threadIdx.x & 63;
  int rbase = blockIdx.x * 128 + wv * 32;
  int lr = lane & 15, lk = (lane >> 4) * 8;
  f32x4 acc0[13], acc1[13];
#pragma unroll
  for (int j = 0; j < 13; j++) {
    acc0[j] = (f32x4){0.f, 0.f, 0.f, 0.f};
    acc1[j] = (f32x4){0.f, 0.f, 0.f, 0.f};
  }
#pragma unroll
  for (int s = 0; s < 10; s++) {
    bf16x8 a0 = *(const bf16x8*)(h1b + (size_t)(rbase + lr) * 320 + s * 32 + lk);
    bf16x8 a1 = *(const bf16x8*)(h1b + (size_t)(rbase + 16 + lr) * 320 + s * 32 + lk);
#pragma unroll
    for (int j = 0; j < 13; j++) {
      bf16x8 b = *(const bf16x8*)(Wt2 + (size_t)(j * 16 + lr) * 320 + s * 32 + lk);
      acc0[j] = __builtin_amdgcn_mfma_f32_16x16x32_bf16(a0, b, acc0[j], 0, 0, 0);
      acc1[j] = __builtin_amdgcn_mfma_f32_16x16x32_bf16(a1, b, acc1[j], 0, 0, 0);
    }
  }
  int r0 = (lane >> 4) * 4;
#pragma unroll
  for (int j = 0; j < 13; j++) {
    int c = j * 16 + lr;
#pragma unroll
    for (int i = 0; i < 4; i++) {
      tile[wv][r0 + i][c] = (unsigned short)f2bf(acc0[j][i]);
      tile[wv][r0 + 16 + i][c] = (unsigned short)f2bf(acc1[j][i]);
    }
  }
  // wave tile = rows rbase..rbase+31, 208 cols -> 13312 contiguous bytes
  const uint4* lsrc = (const uint4*)&tile[wv][0][0];
  uint4* gdst = (uint4*)(ga2b + (size_t)rbase * 208);
  for (int idx = lane; idx < 832; idx += 64) gdst[idx] = lsrc[idx];
}

// ---------------- launch ----------------
extern "C" void kernel_launch(void* const* d_in, const int* in_sizes, int n_in,
                              void* d_out, int out_size, void* d_ws, size_t ws_size,
                              hipStream_t stream) {
  const float* x  = (const float*)d_in[0];
  const int*   ei = (const int*)d_in[1];
  const float* W1 = (const float*)d_in[2];  // [2][58][300]
  const float* b1 = (const float*)d_in[3];
  const float* W2 = (const float*)d_in[4];  // [2][300][100]
  const float* b2 = (const float*)d_in[5];
  const float* W3 = (const float*)d_in[6];  // [2][100][1]
  const float* b3 = (const float*)d_in[7];
  float* out = (float*)d_out;

  const int N = in_sizes[0] / 58;            // 100000
  const int E = in_sizes[1] / 2;             // 800000
  const int NR = (N + 127) & ~127;           // 100096
  const int NB = (N + 1023) / 1024;
  const int* src = ei;
  const int* dst = ei + E;

  char* ws = (char*)d_ws;
  size_t off = 0;
  auto alloc = [&](size_t bytes) -> void* {
    void* p = ws + off;
    off += (bytes + 255) & ~(size_t)255;
    return p;
  };
  unsigned* deg      = (unsigned*)alloc((size_t)2 * N * 4);
  unsigned* cnt      = deg + N;
  float*    dinv     = (float*)alloc((size_t)N * 4);
  unsigned* rowstart = (unsigned*)alloc((size_t)(N + 1) * 4);
  unsigned* cursor   = (unsigned*)alloc((size_t)N * 4);
  unsigned* btot     = (unsigned*)alloc((size_t)256 * 4);
  int2*     er       = (int2*)alloc((size_t)E * 8);
  unsigned short* xb   = (unsigned short*)alloc((size_t)NR * 128 * 2);
  unsigned short* Wt1  = (unsigned short*)alloc((size_t)304 * 128 * 2);
  unsigned short* Wt2  = (unsigned short*)alloc((size_t)208 * 320 * 2);
  unsigned short* h1b  = (unsigned short*)alloc((size_t)NR * 320 * 2);
  unsigned short* ga2b = (unsigned short*)alloc((size_t)NR * 208 * 2);
  float* a3 = (float*)alloc((size_t)N * 4);
  float* g3 = (float*)alloc((size_t)N * 4);

  // --- CSR + dinv ---
  hipMemsetAsync(deg, 0, (size_t)2 * N * 4, stream);
  k_count<<<(E + 255) / 256, 256, 0, stream>>>(src, dst, deg, cnt, E);
  k_dinv<<<(N + 255) / 256, 256, 0, stream>>>(deg, dinv, N);
  k_scan1<<<NB, 256, 0, stream>>>(cnt, btot, N);
  k_scan2<<<1, 256, 0, stream>>>(btot, rowstart, NB, N, E);
  k_scan3<<<NB, 256, 0, stream>>>(cnt, btot, rowstart, cursor, N);
  k_fill<<<(E + 255) / 256, 256, 0, stream>>>(src, dst, dinv, cursor, er, E);

  // --- preps ---
  k_prep_w1<<<(304 * 64 + 255) / 256, 256, 0, stream>>>(W1, Wt1);
  k_prep_w2<<<(208 * 160 + 255) / 256, 256, 0, stream>>>(W2, Wt2);
  k_prep_xb<<<((size_t)N * 64 + 255) / 256, 256, 0, stream>>>(x, xb, N);

  // --- layer 1 ---
  k_gather58<<<(N + 3) / 4, 256, 0, stream>>>(rowstart, er, dinv, xb, N);
  k_mm1_mfma<<<NR / 128, 256, 0, stream>>>(xb, Wt1, b1, h1b);

  // --- layer 2 ---
  k_mm2_mfma<<<NR / 128, 256, 0, stream>>>(h1b, Wt2, ga2b);
  k_gather_l2<<<(N + 3) / 4, 256, 0, stream>>>(rowstart, er, dinv, ga2b,
                                               b2, W3, W3 + 100, b3, a3, g3, N);

  // --- layer 3 ---
  k_gather1<<<(N + 255) / 256, 256, 0, stream>>>(rowstart, er, dinv, g3, a3, out, N);
}

// Round 8
// 382.202 us; speedup vs baseline: 1.0896x; 1.0896x over previous
//
#include <hip/hip_runtime.h>

// ---------------------------------------------------------------------------
// EMOGI ChebConv-K2 x3 : N=100000 nodes, E=800000 edges, dims 58->300->100->1
//   CSR by dst (count/scan/fill) -> gathers, no float atomics.
//   xb  [NR][128] bf16 = [x | p1 | 0]       (p1 filled by gather58)
//   h1b [NR][320] bf16 = relu([x|p1]@[W10;W11] + b1), cols 300..319 = 0
//   mm2: ga2b[NR][208] = h1b @ [W21|pad|W20|pad]  (cols 0..99 g2, 104..203 a2)
//   gather_l2: p2 = prop(g2); h2 = relu(a2+p2+b2) in-reg; a3,g3 = h2@W3 dots
//   gather1: out = a3 + prop(g3)
//
// R7 lesson: all LDS-C-staged mm variants ran 78-92us at MfmaUtil ~6% --
// latency-bound: 3 LDS-capped blocks/CU, B-panel re-read per wave from L2,
// 640B-strided frag loads. Rebuild:
//  * swapped mfma(W,X): lane owns 4 consecutive out-cols of ONE node row ->
//    direct 8B packed bf16 stores (adjacent j-tiles complete 64B lines).
//  * weights pre-packed in fragment order [s][j][lane][16B]: staging =
//    contiguous memcpy, slab ds_read_b128 lane-linear = conflict-free,
//    panel read once per 64-node block (not once per wave).
//  * 16-node wave-tiles, 256-thr blocks, LDS 13-20KB -> 16-20 waves/CU.
// ---------------------------------------------------------------------------

typedef short bf16x8 __attribute__((ext_vector_type(8)));
typedef float f32x4 __attribute__((ext_vector_type(4)));

__device__ __forceinline__ unsigned f2bf(float f) {  // RNE fp32->bf16 bits
  unsigned u = __float_as_uint(f);
  u += 0x7fff + ((u >> 16) & 1);
  return u >> 16;
}
__device__ __forceinline__ float bf2f(unsigned s) {
  return __uint_as_float(s << 16);
}

// ---------------- CSR build ----------------
__global__ void k_count(const int* __restrict__ src, const int* __restrict__ dst,
                        unsigned* __restrict__ deg, unsigned* __restrict__ cnt, int E) {
  int i = blockIdx.x * blockDim.x + threadIdx.x;
  if (i < E) {
    atomicAdd(&deg[src[i]], 1u);
    atomicAdd(&cnt[dst[i]], 1u);
  }
}

__global__ void k_dinv(const unsigned* __restrict__ deg, float* __restrict__ dinv, int N) {
  int i = blockIdx.x * blockDim.x + threadIdx.x;
  if (i < N) {
    unsigned d = deg[i];
    dinv[i] = d ? rsqrtf((float)d) : 0.0f;
  }
}

__global__ __launch_bounds__(256) void k_scan1(const unsigned* __restrict__ cnt,
                                               unsigned* __restrict__ btot, int N) {
  __shared__ unsigned s[256];
  int b = blockIdx.x, t = threadIdx.x;
  int base = b * 1024;
  unsigned sum = 0;
  for (int i = t; i < 1024; i += 256) {
    int idx = base + i;
    sum += (idx < N) ? cnt[idx] : 0u;
  }
  s[t] = sum;
  __syncthreads();
  for (int off = 128; off > 0; off >>= 1) {
    if (t < off) s[t] += s[t + off];
    __syncthreads();
  }
  if (t == 0) btot[b] = s[0];
}

__global__ __launch_bounds__(256) void k_scan2(unsigned* __restrict__ btot,
                                               unsigned* __restrict__ rowstart,
                                               int NB, int N, int E) {
  __shared__ unsigned s[256];
  int t = threadIdx.x;
  s[t] = (t < NB) ? btot[t] : 0u;
  __syncthreads();
  if (t == 0) {
    unsigned acc = 0;
    for (int i = 0; i < NB; i++) { unsigned v = s[i]; s[i] = acc; acc += v; }
  }
  __syncthreads();
  if (t < NB) btot[t] = s[t];
  if (t == 0) rowstart[N] = (unsigned)E;
}

__global__ __launch_bounds__(256) void k_scan3(const unsigned* __restrict__ cnt,
                                               const unsigned* __restrict__ btot,
                                               unsigned* __restrict__ rowstart,
                                               unsigned* __restrict__ cursor, int N) {
  __shared__ unsigned ssum[256];
  int b = blockIdx.x, t = threadIdx.x;
  int base = b * 1024 + t * 4;
  unsigned v0 = 0, v1 = 0, v2 = 0, v3 = 0;
  if (base + 0 < N) v0 = cnt[base + 0];
  if (base + 1 < N) v1 = cnt[base + 1];
  if (base + 2 < N) v2 = cnt[base + 2];
  if (base + 3 < N) v3 = cnt[base + 3];
  ssum[t] = v0 + v1 + v2 + v3;
  __syncthreads();
  for (int off = 1; off < 256; off <<= 1) {
    unsigned add = (t >= off) ? ssum[t - off] : 0u;
    __syncthreads();
    ssum[t] += add;
    __syncthreads();
  }
  unsigned texcl = ((t == 0) ? 0u : ssum[t - 1]) + btot[b];
  unsigned r0 = texcl, r1 = r0 + v0, r2 = r1 + v1, r3 = r2 + v2;
  if (base + 0 < N) { rowstart[base + 0] = r0; cursor[base + 0] = r0; }
  if (base + 1 < N) { rowstart[base + 1] = r1; cursor[base + 1] = r1; }
  if (base + 2 < N) { rowstart[base + 2] = r2; cursor[base + 2] = r2; }
  if (base + 3 < N) { rowstart[base + 3] = r3; cursor[base + 3] = r3; }
}

__global__ void k_fill(const int* __restrict__ src, const int* __restrict__ dst,
                       const float* __restrict__ dinv, unsigned* __restrict__ cursor,
                       int2* __restrict__ er, int E) {
  int e = blockIdx.x * blockDim.x + threadIdx.x;
  if (e >= E) return;
  int s = src[e], d = dst[e];
  unsigned pos = atomicAdd(&cursor[d], 1u);
  er[pos] = make_int2(s, __float_as_int(dinv[s]));
}

// ---------------- prep kernels ----------------
__global__ void k_prep_xb(const float* __restrict__ x, unsigned short* __restrict__ xb, int N) {
  int idx = blockIdx.x * blockDim.x + threadIdx.x;
  int n = idx >> 6, p = idx & 63;
  if (n >= N) return;
  int c = p * 2;
  if (c < 58) {
    unsigned lo = f2bf(x[(size_t)n * 58 + c]);
    unsigned hi = f2bf(x[(size_t)n * 58 + c + 1]);
    *(unsigned*)(xb + (size_t)n * 128 + c) = lo | (hi << 16);
  } else if (c >= 116) {
    *(unsigned*)(xb + (size_t)n * 128 + c) = 0;
  }
}

// W1f fragment-packed [s<4][j<20][lane<64][8 bf16]:
// value = W1cat[k = s*32+(lane>>4)*8+i][c = j*16+(lane&15)]; 0 outside.
__global__ void k_prep_w1f(const float* __restrict__ W1, uint4* __restrict__ W1f) {
  int idx = blockIdx.x * blockDim.x + threadIdx.x;
  if (idx >= 4 * 20 * 64) return;
  int lane = idx & 63, j = (idx >> 6) % 20, s = (idx >> 6) / 20;
  int lr = lane & 15, g = lane >> 4;
  int c = j * 16 + lr;
  unsigned short v[8];
#pragma unroll
  for (int i = 0; i < 8; i++) {
    int k = s * 32 + g * 8 + i;
    float f = 0.0f;
    if (c < 300 && k < 116)
      f = (k < 58) ? W1[k * 300 + c] : W1[17400 + (k - 58) * 300 + c];
    v[i] = (unsigned short)f2bf(f);
  }
  W1f[idx] = *(const uint4*)v;
}

// W2f fragment-packed [s<10][j<13][lane<64][8 bf16]:
// rows r=j*16+lr: r<100 -> W21[k][r] (g2) ; 104<=r<204 -> W20[k][r-104] (a2).
__global__ void k_prep_w2f(const float* __restrict__ W2, uint4* __restrict__ W2f) {
  int idx = blockIdx.x * blockDim.x + threadIdx.x;
  if (idx >= 10 * 13 * 64) return;
  int lane = idx & 63, j = (idx >> 6) % 13, s = (idx >> 6) / 13;
  int lr = lane & 15, g = lane >> 4;
  int r = j * 16 + lr;
  unsigned short v[8];
#pragma unroll
  for (int i = 0; i < 8; i++) {
    int k = s * 32 + g * 8 + i;
    float f = 0.0f;
    if (k < 300) {
      if (r < 100) f = W2[30000 + k * 100 + r];
      else if (r >= 104 && r < 204) f = W2[k * 100 + (r - 104)];
    }
    v[i] = (unsigned short)f2bf(f);
  }
  W2f[idx] = *(const uint4*)v;
}

__global__ void k_prep_b1pad(const float* __restrict__ b1, float* __restrict__ b1pad) {
  int t = blockIdx.x * blockDim.x + threadIdx.x;
  if (t < 320) b1pad[t] = (t < 300) ? b1[t] : 0.0f;
}

// ---------------- gathers (x4 MLP-unrolled) ----------------
__global__ __launch_bounds__(256) void k_gather58(
    const unsigned* __restrict__ rowstart, const int2* __restrict__ er,
    const float* __restrict__ dinv, unsigned short* __restrict__ xb, int N) {
  int wid = (blockIdx.x * blockDim.x + threadIdx.x) >> 6;
  if (wid >= N) return;
  int lane = threadIdx.x & 63;
  int c0 = lane * 2;
  if (c0 >= 58) return;
  unsigned s0 = rowstart[wid], s1 = rowstart[wid + 1];
  float a0 = 0.f, a1 = 0.f, b0 = 0.f, b1 = 0.f;
  float c0a = 0.f, c1a = 0.f, d0 = 0.f, d1 = 0.f;
  unsigned e = s0;
  for (; e + 4 <= s1; e += 4) {
    int2 r0 = er[e], r1 = er[e + 1], r2 = er[e + 2], r3 = er[e + 3];
    unsigned v0 = *(const unsigned*)(xb + (size_t)r0.x * 128 + c0);
    unsigned v1 = *(const unsigned*)(xb + (size_t)r1.x * 128 + c0);
    unsigned v2 = *(const unsigned*)(xb + (size_t)r2.x * 128 + c0);
    unsigned v3 = *(const unsigned*)(xb + (size_t)r3.x * 128 + c0);
    float w0 = __int_as_float(r0.y), w1 = __int_as_float(r1.y);
    float w2 = __int_as_float(r2.y), w3 = __int_as_float(r3.y);
    a0 += w0 * bf2f(v0 & 0xffffu); a1 += w0 * bf2f(v0 >> 16);
    b0 += w1 * bf2f(v1 & 0xffffu); b1 += w1 * bf2f(v1 >> 16);
    c0a += w2 * bf2f(v2 & 0xffffu); c1a += w2 * bf2f(v2 >> 16);
    d0 += w3 * bf2f(v3 & 0xffffu); d1 += w3 * bf2f(v3 >> 16);
  }
  for (; e < s1; ++e) {
    int2 r = er[e];
    float w = __int_as_float(r.y);
    unsigned v = *(const unsigned*)(xb + (size_t)r.x * 128 + c0);
    a0 += w * bf2f(v & 0xffffu); a1 += w * bf2f(v >> 16);
  }
  float dd = -dinv[wid];
  float p0 = dd * ((a0 + b0) + (c0a + d0));
  float p1 = dd * ((a1 + b1) + (c1a + d1));
  *(unsigned*)(xb + (size_t)wid * 128 + 58 + c0) = f2bf(p0) | (f2bf(p1) << 16);
}

// layer2 tail fused: p2 = prop(g2); h2 = relu(a2+p2+b2); a3,g3 = h2@W30/W31
__global__ __launch_bounds__(256) void k_gather_l2(
    const unsigned* __restrict__ rowstart, const int2* __restrict__ er,
    const float* __restrict__ dinv, const unsigned short* __restrict__ ga2b,
    const float* __restrict__ b2, const float* __restrict__ W30,
    const float* __restrict__ W31, const float* __restrict__ b3,
    float* __restrict__ a3, float* __restrict__ g3, int N) {
  int wid = (blockIdx.x * blockDim.x + threadIdx.x) >> 6;
  if (wid >= N) return;
  int lane = threadIdx.x & 63;
  int c0 = lane * 2;
  bool act = c0 < 100;
  unsigned s0 = rowstart[wid], s1 = rowstart[wid + 1];
  float aa = 0.f, gg = 0.f;
  if (act) {
    float a0 = 0.f, a1 = 0.f, b0 = 0.f, b1 = 0.f;
    float c0a = 0.f, c1a = 0.f, d0 = 0.f, d1 = 0.f;
    unsigned e = s0;
    for (; e + 4 <= s1; e += 4) {
      int2 r0 = er[e], r1 = er[e + 1], r2 = er[e + 2], r3 = er[e + 3];
      unsigned v0 = *(const unsigned*)(ga2b + (size_t)r0.x * 208 + c0);
      unsigned v1 = *(const unsigned*)(ga2b + (size_t)r1.x * 208 + c0);
      unsigned v2 = *(const unsigned*)(ga2b + (size_t)r2.x * 208 + c0);
      unsigned v3 = *(const unsigned*)(ga2b + (size_t)r3.x * 208 + c0);
      float w0 = __int_as_float(r0.y), w1 = __int_as_float(r1.y);
      float w2 = __int_as_float(r2.y), w3 = __int_as_float(r3.y);
      a0 += w0 * bf2f(v0 & 0xffffu); a1 += w0 * bf2f(v0 >> 16);
      b0 += w1 * bf2f(v1 & 0xffffu); b1 += w1 * bf2f(v1 >> 16);
      c0a += w2 * bf2f(v2 & 0xffffu); c1a += w2 * bf2f(v2 >> 16);
      d0 += w3 * bf2f(v3 & 0xffffu); d1 += w3 * bf2f(v3 >> 16);
    }
    for (; e < s1; ++e) {
      int2 r = er[e];
      float w = __int_as_float(r.y);
      unsigned v = *(const unsigned*)(ga2b + (size_t)r.x * 208 + c0);
      a0 += w * bf2f(v & 0xffffu); a1 += w * bf2f(v >> 16);
    }
    float dd = -dinv[wid];
    float p0 = dd * ((a0 + b0) + (c0a + d0));
    float p1 = dd * ((a1 + b1) + (c1a + d1));
    unsigned av = *(const unsigned*)(ga2b + (size_t)wid * 208 + 104 + c0);
    float h0 = fmaxf(bf2f(av & 0xffffu) + p0 + b2[c0], 0.f);
    float h1 = fmaxf(bf2f(av >> 16) + p1 + b2[c0 + 1], 0.f);
    aa = h0 * W30[c0] + h1 * W30[c0 + 1];
    gg = h0 * W31[c0] + h1 * W31[c0 + 1];
  }
#pragma unroll
  for (int off = 32; off > 0; off >>= 1) {
    aa += __shfl_xor(aa, off);
    gg += __shfl_xor(gg, off);
  }
  if (lane == 0) {
    a3[wid] = aa + b3[0];
    g3[wid] = gg;
  }
}

__global__ void k_gather1(const unsigned* __restrict__ rowstart, const int2* __restrict__ er,
                          const float* __restrict__ dinv, const float* __restrict__ g3,
                          const float* __restrict__ a3, float* __restrict__ out, int N) {
  int n = blockIdx.x * blockDim.x + threadIdx.x;
  if (n >= N) return;
  unsigned s0 = rowstart[n], s1 = rowstart[n + 1];
  float a = 0.f, b = 0.f, c = 0.f, d = 0.f;
  unsigned e = s0;
  for (; e + 4 <= s1; e += 4) {
    int2 r0 = er[e], r1 = er[e + 1], r2 = er[e + 2], r3 = er[e + 3];
    float g0 = g3[r0.x], g1 = g3[r1.x], g2v = g3[r2.x], g3v = g3[r3.x];
    a += __int_as_float(r0.y) * g0;
    b += __int_as_float(r1.y) * g1;
    c += __int_as_float(r2.y) * g2v;
    d += __int_as_float(r3.y) * g3v;
  }
  for (; e < s1; ++e) {
    int2 r = er[e];
    a += __int_as_float(r.y) * g3[r.x];
  }
  out[n] = a3[n] - dinv[n] * ((a + b) + (c + d));
}

// ---------------- MFMA matmuls (swapped-operand, slab-shared W) -------------
// h1b = relu(xb @ W1 + b1) over 320 cols (300 real + 20 auto-zero pad).
// Block: 4 waves x 16 nodes. Per s: stage W slab (20KB, memcpy-contiguous),
// 2 barriers, then per wave 1 X-load + 20 conflict-free ds_read + 20 mfma.
// mfma(w,a): lane&15 = node, reg (lane>>4)*4+i = out-col -> 8B packed store.
__global__ __launch_bounds__(256) void k_mm1_mfma(
    const unsigned short* __restrict__ xb, const uint4* __restrict__ W1f,
    const float* __restrict__ b1pad, unsigned short* __restrict__ h1b) {
  __shared__ uint4 slab[1280];  // 20 KB
  int tid = threadIdx.x;
  int lane = tid & 63, wv = tid >> 6, lr = lane & 15, g = lane >> 4;
  int n0 = blockIdx.x * 64 + wv * 16;
  f32x4 acc[20];
#pragma unroll
  for (int j = 0; j < 20; j++) acc[j] = (f32x4){0.f, 0.f, 0.f, 0.f};
#pragma unroll
  for (int s = 0; s < 4; s++) {
    uint4 st[5];
#pragma unroll
    for (int q = 0; q < 5; q++) st[q] = W1f[s * 1280 + q * 256 + tid];
    __syncthreads();  // previous slab fully consumed
#pragma unroll
    for (int q = 0; q < 5; q++) slab[q * 256 + tid] = st[q];
    __syncthreads();  // new slab ready
    bf16x8 a = *(const bf16x8*)(xb + (size_t)(n0 + lr) * 128 + s * 32 + g * 8);
#pragma unroll
    for (int j = 0; j < 20; j++) {
      bf16x8 w = *(const bf16x8*)&slab[j * 64 + lane];
      acc[j] = __builtin_amdgcn_mfma_f32_16x16x32_bf16(w, a, acc[j], 0, 0, 0);
    }
  }
  size_t rowb = (size_t)(n0 + lr) * 320;
#pragma unroll
  for (int j = 0; j < 20; j++) {
    float4 bv = *(const float4*)(b1pad + j * 16 + g * 4);
    unsigned lo = f2bf(fmaxf(acc[j][0] + bv.x, 0.f)) |
                  (f2bf(fmaxf(acc[j][1] + bv.y, 0.f)) << 16);
    unsigned hi = f2bf(fmaxf(acc[j][2] + bv.z, 0.f)) |
                  (f2bf(fmaxf(acc[j][3] + bv.w, 0.f)) << 16);
    uint2 pk; pk.x = lo; pk.y = hi;
    *(uint2*)(h1b + rowb + j * 16 + g * 4) = pk;
  }
}

// ga2b = h1b @ [W21|pad|W20|pad]. 13 col-tiles, K=320 (10 s-steps).
__global__ __launch_bounds__(256) void k_mm2_mfma(
    const unsigned short* __restrict__ h1b, const uint4* __restrict__ W2f,
    unsigned short* __restrict__ ga2b) {
  __shared__ uint4 slab[832];  // 13 KB
  int tid = threadIdx.x;
  int lane = tid & 63, wv = tid >> 6, lr = lane & 15, g = lane >> 4;
  int n0 = blockIdx.x * 64 + wv * 16;
  f32x4 acc[13];
#pragma unroll
  for (int j = 0; j < 13; j++) acc[j] = (f32x4){0.f, 0.f, 0.f, 0.f};
#pragma unroll
  for (int s = 0; s < 10; s++) {
    uint4 st0 = W2f[s * 832 + tid];
    uint4 st1 = W2f[s * 832 + 256 + tid];
    uint4 st2 = W2f[s * 832 + 512 + tid];
    uint4 st3 = {0, 0, 0, 0};
    if (tid < 64) st3 = W2f[s * 832 + 768 + tid];
    __syncthreads();  // previous slab fully consumed
    slab[tid] = st0;
    slab[256 + tid] = st1;
    slab[512 + tid] = st2;
    if (tid < 64) slab[768 + tid] = st3;
    __syncthreads();  // new slab ready
    bf16x8 a = *(const bf16x8*)(h1b + (size_t)(n0 + lr) * 320 + s * 32 + g * 8);
#pragma unroll
    for (int j = 0; j < 13; j++) {
      bf16x8 w = *(const bf16x8*)&slab[j * 64 + lane];
      acc[j] = __builtin_amdgcn_mfma_f32_16x16x32_bf16(w, a, acc[j], 0, 0, 0);
    }
  }
  size_t rowb = (size_t)(n0 + lr) * 208;
#pragma unroll
  for (int j = 0; j < 13; j++) {
    unsigned lo = f2bf(acc[j][0]) | (f2bf(acc[j][1]) << 16);
    unsigned hi = f2bf(acc[j][2]) | (f2bf(acc[j][3]) << 16);
    uint2 pk; pk.x = lo; pk.y = hi;
    *(uint2*)(ga2b + rowb + j * 16 + g * 4) = pk;
  }
}

// ---------------- launch ----------------
extern "C" void kernel_launch(void* const* d_in, const int* in_sizes, int n_in,
                              void* d_out, int out_size, void* d_ws, size_t ws_size,
                              hipStream_t stream) {
  const float* x  = (const float*)d_in[0];
  const int*   ei = (const int*)d_in[1];
  const float* W1 = (const float*)d_in[2];  // [2][58][300]
  const float* b1 = (const float*)d_in[3];
  const float* W2 = (const float*)d_in[4];  // [2][300][100]
  const float* b2 = (const float*)d_in[5];
  const float* W3 = (const float*)d_in[6];  // [2][100][1]
  const float* b3 = (const float*)d_in[7];
  float* out = (float*)d_out;

  const int N = in_sizes[0] / 58;            // 100000
  const int E = in_sizes[1] / 2;             // 800000
  const int NR = (N + 127) & ~127;           // 100096 (multiple of 64)
  const int NB = (N + 1023) / 1024;
  const int* src = ei;
  const int* dst = ei + E;

  char* ws = (char*)d_ws;
  size_t off = 0;
  auto alloc = [&](size_t bytes) -> void* {
    void* p = ws + off;
    off += (bytes + 255) & ~(size_t)255;
    return p;
  };
  unsigned* deg      = (unsigned*)alloc((size_t)2 * N * 4);
  unsigned* cnt      = deg + N;
  float*    dinv     = (float*)alloc((size_t)N * 4);
  unsigned* rowstart = (unsigned*)alloc((size_t)(N + 1) * 4);
  unsigned* cursor   = (unsigned*)alloc((size_t)N * 4);
  unsigned* btot     = (unsigned*)alloc((size_t)256 * 4);
  int2*     er       = (int2*)alloc((size_t)E * 8);
  unsigned short* xb   = (unsigned short*)alloc((size_t)NR * 128 * 2);
  uint4*    W1f      = (uint4*)alloc((size_t)4 * 20 * 64 * 16);   // 80 KB
  uint4*    W2f      = (uint4*)alloc((size_t)10 * 13 * 64 * 16);  // 133 KB
  float*    b1pad    = (float*)alloc((size_t)320 * 4);
  unsigned short* h1b  = (unsigned short*)alloc((size_t)NR * 320 * 2);
  unsigned short* ga2b = (unsigned short*)alloc((size_t)NR * 208 * 2);
  float* a3 = (float*)alloc((size_t)N * 4);
  float* g3 = (float*)alloc((size_t)N * 4);

  // --- CSR + dinv ---
  hipMemsetAsync(deg, 0, (size_t)2 * N * 4, stream);
  k_count<<<(E + 255) / 256, 256, 0, stream>>>(src, dst, deg, cnt, E);
  k_dinv<<<(N + 255) / 256, 256, 0, stream>>>(deg, dinv, N);
  k_scan1<<<NB, 256, 0, stream>>>(cnt, btot, N);
  k_scan2<<<1, 256, 0, stream>>>(btot, rowstart, NB, N, E);
  k_scan3<<<NB, 256, 0, stream>>>(cnt, btot, rowstart, cursor, N);
  k_fill<<<(E + 255) / 256, 256, 0, stream>>>(src, dst, dinv, cursor, er, E);

  // --- preps ---
  k_prep_w1f<<<(4 * 20 * 64 + 255) / 256, 256, 0, stream>>>(W1, W1f);
  k_prep_w2f<<<(10 * 13 * 64 + 255) / 256, 256, 0, stream>>>(W2, W2f);
  k_prep_b1pad<<<2, 256, 0, stream>>>(b1, b1pad);
  k_prep_xb<<<((size_t)N * 64 + 255) / 256, 256, 0, stream>>>(x, xb, N);

  // --- layer 1 ---
  k_gather58<<<(N + 3) / 4, 256, 0, stream>>>(rowstart, er, dinv, xb, N);
  k_mm1_mfma<<<NR / 64, 256, 0, stream>>>(xb, W1f, b1pad, h1b);

  // --- layer 2 ---
  k_mm2_mfma<<<NR / 64, 256, 0, stream>>>(h1b, W2f, ga2b);
  k_gather_l2<<<(N + 3) / 4, 256, 0, stream>>>(rowstart, er, dinv, ga2b,
                                               b2, W3, W3 + 100, b3, a3, g3, N);

  // --- layer 3 ---
  k_gather1<<<(N + 255) / 256, 256, 0, stream>>>(rowstart, er, dinv, g3, a3, out, N);
}

// Round 9
// 356.542 us; speedup vs baseline: 1.1681x; 1.0720x over previous
//
#include <hip/hip_runtime.h>

// ---------------------------------------------------------------------------
// EMOGI ChebConv-K2 x3 : N=100000 nodes, E=800000 edges, dims 58->300->100->1
//   CSR by dst (count/scan/fill) -> gathers, no float atomics.
//   xb  [NR][128] bf16 = [x | p1 | 0]       (p1 filled by gather58)
//   h1b [NR][320] bf16 = relu([x|p1]@[W10;W11] + b1), cols 300..319 = 0
//   mm2: ga2b[NR][208] = h1b @ [W21|pad|W20|pad]  (cols 0..99 g2, 104..203 a2)
//   gather_l2: p2 = prop(g2); h2 = relu(a2+p2+b2) in-reg; a3,g3 = h2@W3 dots
//   gather1: out = a3 + prop(g3)
//
// R8 lesson: swapped-operand mfma(W,X) + fragment-packed W slabs fixed the
// latency chase, but DIRECT uint2 C-stores write 16x32B half-lines per
// instruction -> 64B RMW at L2: mm1 WRITE_SIZE 174.6MB for 64MB payload,
// 87us store-bound. Fix: keep the R8 compute structure, re-attach the R5
// LDS-staged epilogue (proven clean writes), REUSING the slab LDS after a
// barrier (union) so occupancy is unchanged. mm1 copies 320B full-line row
// runs; mm2 one contiguous 6656B span per wave.
// ---------------------------------------------------------------------------

typedef short bf16x8 __attribute__((ext_vector_type(8)));
typedef float f32x4 __attribute__((ext_vector_type(4)));

__device__ __forceinline__ unsigned f2bf(float f) {  // RNE fp32->bf16 bits
  unsigned u = __float_as_uint(f);
  u += 0x7fff + ((u >> 16) & 1);
  return u >> 16;
}
__device__ __forceinline__ float bf2f(unsigned s) {
  return __uint_as_float(s << 16);
}

// ---------------- CSR build ----------------
__global__ void k_count(const int* __restrict__ src, const int* __restrict__ dst,
                        unsigned* __restrict__ deg, unsigned* __restrict__ cnt, int E) {
  int i = blockIdx.x * blockDim.x + threadIdx.x;
  if (i < E) {
    atomicAdd(&deg[src[i]], 1u);
    atomicAdd(&cnt[dst[i]], 1u);
  }
}

__global__ void k_dinv(const unsigned* __restrict__ deg, float* __restrict__ dinv, int N) {
  int i = blockIdx.x * blockDim.x + threadIdx.x;
  if (i < N) {
    unsigned d = deg[i];
    dinv[i] = d ? rsqrtf((float)d) : 0.0f;
  }
}

__global__ __launch_bounds__(256) void k_scan1(const unsigned* __restrict__ cnt,
                                               unsigned* __restrict__ btot, int N) {
  __shared__ unsigned s[256];
  int b = blockIdx.x, t = threadIdx.x;
  int base = b * 1024;
  unsigned sum = 0;
  for (int i = t; i < 1024; i += 256) {
    int idx = base + i;
    sum += (idx < N) ? cnt[idx] : 0u;
  }
  s[t] = sum;
  __syncthreads();
  for (int off = 128; off > 0; off >>= 1) {
    if (t < off) s[t] += s[t + off];
    __syncthreads();
  }
  if (t == 0) btot[b] = s[0];
}

__global__ __launch_bounds__(256) void k_scan2(unsigned* __restrict__ btot,
                                               unsigned* __restrict__ rowstart,
                                               int NB, int N, int E) {
  __shared__ unsigned s[256];
  int t = threadIdx.x;
  s[t] = (t < NB) ? btot[t] : 0u;
  __syncthreads();
  if (t == 0) {
    unsigned acc = 0;
    for (int i = 0; i < NB; i++) { unsigned v = s[i]; s[i] = acc; acc += v; }
  }
  __syncthreads();
  if (t < NB) btot[t] = s[t];
  if (t == 0) rowstart[N] = (unsigned)E;
}

__global__ __launch_bounds__(256) void k_scan3(const unsigned* __restrict__ cnt,
                                               const unsigned* __restrict__ btot,
                                               unsigned* __restrict__ rowstart,
                                               unsigned* __restrict__ cursor, int N) {
  __shared__ unsigned ssum[256];
  int b = blockIdx.x, t = threadIdx.x;
  int base = b * 1024 + t * 4;
  unsigned v0 = 0, v1 = 0, v2 = 0, v3 = 0;
  if (base + 0 < N) v0 = cnt[base + 0];
  if (base + 1 < N) v1 = cnt[base + 1];
  if (base + 2 < N) v2 = cnt[base + 2];
  if (base + 3 < N) v3 = cnt[base + 3];
  ssum[t] = v0 + v1 + v2 + v3;
  __syncthreads();
  for (int off = 1; off < 256; off <<= 1) {
    unsigned add = (t >= off) ? ssum[t - off] : 0u;
    __syncthreads();
    ssum[t] += add;
    __syncthreads();
  }
  unsigned texcl = ((t == 0) ? 0u : ssum[t - 1]) + btot[b];
  unsigned r0 = texcl, r1 = r0 + v0, r2 = r1 + v1, r3 = r2 + v2;
  if (base + 0 < N) { rowstart[base + 0] = r0; cursor[base + 0] = r0; }
  if (base + 1 < N) { rowstart[base + 1] = r1; cursor[base + 1] = r1; }
  if (base + 2 < N) { rowstart[base + 2] = r2; cursor[base + 2] = r2; }
  if (base + 3 < N) { rowstart[base + 3] = r3; cursor[base + 3] = r3; }
}

__global__ void k_fill(const int* __restrict__ src, const int* __restrict__ dst,
                       const float* __restrict__ dinv, unsigned* __restrict__ cursor,
                       int2* __restrict__ er, int E) {
  int e = blockIdx.x * blockDim.x + threadIdx.x;
  if (e >= E) return;
  int s = src[e], d = dst[e];
  unsigned pos = atomicAdd(&cursor[d], 1u);
  er[pos] = make_int2(s, __float_as_int(dinv[s]));
}

// ---------------- prep kernels ----------------
__global__ void k_prep_xb(const float* __restrict__ x, unsigned short* __restrict__ xb, int N) {
  int idx = blockIdx.x * blockDim.x + threadIdx.x;
  int n = idx >> 6, p = idx & 63;
  if (n >= N) return;
  int c = p * 2;
  if (c < 58) {
    unsigned lo = f2bf(x[(size_t)n * 58 + c]);
    unsigned hi = f2bf(x[(size_t)n * 58 + c + 1]);
    *(unsigned*)(xb + (size_t)n * 128 + c) = lo | (hi << 16);
  } else if (c >= 116) {
    *(unsigned*)(xb + (size_t)n * 128 + c) = 0;
  }
}

// W1f fragment-packed [s<4][j<20][lane<64][8 bf16]:
// value = W1cat[k = s*32+(lane>>4)*8+i][c = j*16+(lane&15)]; 0 outside.
__global__ void k_prep_w1f(const float* __restrict__ W1, uint4* __restrict__ W1f) {
  int idx = blockIdx.x * blockDim.x + threadIdx.x;
  if (idx >= 4 * 20 * 64) return;
  int lane = idx & 63, j = (idx >> 6) % 20, s = (idx >> 6) / 20;
  int lr = lane & 15, g = lane >> 4;
  int c = j * 16 + lr;
  unsigned short v[8];
#pragma unroll
  for (int i = 0; i < 8; i++) {
    int k = s * 32 + g * 8 + i;
    float f = 0.0f;
    if (c < 300 && k < 116)
      f = (k < 58) ? W1[k * 300 + c] : W1[17400 + (k - 58) * 300 + c];
    v[i] = (unsigned short)f2bf(f);
  }
  W1f[idx] = *(const uint4*)v;
}

// W2f fragment-packed [s<10][j<13][lane<64][8 bf16]:
// rows r=j*16+lr: r<100 -> W21[k][r] (g2) ; 104<=r<204 -> W20[k][r-104] (a2).
__global__ void k_prep_w2f(const float* __restrict__ W2, uint4* __restrict__ W2f) {
  int idx = blockIdx.x * blockDim.x + threadIdx.x;
  if (idx >= 10 * 13 * 64) return;
  int lane = idx & 63, j = (idx >> 6) % 13, s = (idx >> 6) / 13;
  int lr = lane & 15, g = lane >> 4;
  int r = j * 16 + lr;
  unsigned short v[8];
#pragma unroll
  for (int i = 0; i < 8; i++) {
    int k = s * 32 + g * 8 + i;
    float f = 0.0f;
    if (k < 300) {
      if (r < 100) f = W2[30000 + k * 100 + r];
      else if (r >= 104 && r < 204) f = W2[k * 100 + (r - 104)];
    }
    v[i] = (unsigned short)f2bf(f);
  }
  W2f[idx] = *(const uint4*)v;
}

__global__ void k_prep_b1pad(const float* __restrict__ b1, float* __restrict__ b1pad) {
  int t = blockIdx.x * blockDim.x + threadIdx.x;
  if (t < 320) b1pad[t] = (t < 300) ? b1[t] : 0.0f;
}

// ---------------- gathers (x4 MLP-unrolled) ----------------
__global__ __launch_bounds__(256) void k_gather58(
    const unsigned* __restrict__ rowstart, const int2* __restrict__ er,
    const float* __restrict__ dinv, unsigned short* __restrict__ xb, int N) {
  int wid = (blockIdx.x * blockDim.x + threadIdx.x) >> 6;
  if (wid >= N) return;
  int lane = threadIdx.x & 63;
  int c0 = lane * 2;
  if (c0 >= 58) return;
  unsigned s0 = rowstart[wid], s1 = rowstart[wid + 1];
  float a0 = 0.f, a1 = 0.f, b0 = 0.f, b1 = 0.f;
  float c0a = 0.f, c1a = 0.f, d0 = 0.f, d1 = 0.f;
  unsigned e = s0;
  for (; e + 4 <= s1; e += 4) {
    int2 r0 = er[e], r1 = er[e + 1], r2 = er[e + 2], r3 = er[e + 3];
    unsigned v0 = *(const unsigned*)(xb + (size_t)r0.x * 128 + c0);
    unsigned v1 = *(const unsigned*)(xb + (size_t)r1.x * 128 + c0);
    unsigned v2 = *(const unsigned*)(xb + (size_t)r2.x * 128 + c0);
    unsigned v3 = *(const unsigned*)(xb + (size_t)r3.x * 128 + c0);
    float w0 = __int_as_float(r0.y), w1 = __int_as_float(r1.y);
    float w2 = __int_as_float(r2.y), w3 = __int_as_float(r3.y);
    a0 += w0 * bf2f(v0 & 0xffffu); a1 += w0 * bf2f(v0 >> 16);
    b0 += w1 * bf2f(v1 & 0xffffu); b1 += w1 * bf2f(v1 >> 16);
    c0a += w2 * bf2f(v2 & 0xffffu); c1a += w2 * bf2f(v2 >> 16);
    d0 += w3 * bf2f(v3 & 0xffffu); d1 += w3 * bf2f(v3 >> 16);
  }
  for (; e < s1; ++e) {
    int2 r = er[e];
    float w = __int_as_float(r.y);
    unsigned v = *(const unsigned*)(xb + (size_t)r.x * 128 + c0);
    a0 += w * bf2f(v & 0xffffu); a1 += w * bf2f(v >> 16);
  }
  float dd = -dinv[wid];
  float p0 = dd * ((a0 + b0) + (c0a + d0));
  float p1 = dd * ((a1 + b1) + (c1a + d1));
  *(unsigned*)(xb + (size_t)wid * 128 + 58 + c0) = f2bf(p0) | (f2bf(p1) << 16);
}

// layer2 tail fused: p2 = prop(g2); h2 = relu(a2+p2+b2); a3,g3 = h2@W30/W31
__global__ __launch_bounds__(256) void k_gather_l2(
    const unsigned* __restrict__ rowstart, const int2* __restrict__ er,
    const float* __restrict__ dinv, const unsigned short* __restrict__ ga2b,
    const float* __restrict__ b2, const float* __restrict__ W30,
    const float* __restrict__ W31, const float* __restrict__ b3,
    float* __restrict__ a3, float* __restrict__ g3, int N) {
  int wid = (blockIdx.x * blockDim.x + threadIdx.x) >> 6;
  if (wid >= N) return;
  int lane = threadIdx.x & 63;
  int c0 = lane * 2;
  bool act = c0 < 100;
  unsigned s0 = rowstart[wid], s1 = rowstart[wid + 1];
  float aa = 0.f, gg = 0.f;
  if (act) {
    float a0 = 0.f, a1 = 0.f, b0 = 0.f, b1 = 0.f;
    float c0a = 0.f, c1a = 0.f, d0 = 0.f, d1 = 0.f;
    unsigned e = s0;
    for (; e + 4 <= s1; e += 4) {
      int2 r0 = er[e], r1 = er[e + 1], r2 = er[e + 2], r3 = er[e + 3];
      unsigned v0 = *(const unsigned*)(ga2b + (size_t)r0.x * 208 + c0);
      unsigned v1 = *(const unsigned*)(ga2b + (size_t)r1.x * 208 + c0);
      unsigned v2 = *(const unsigned*)(ga2b + (size_t)r2.x * 208 + c0);
      unsigned v3 = *(const unsigned*)(ga2b + (size_t)r3.x * 208 + c0);
      float w0 = __int_as_float(r0.y), w1 = __int_as_float(r1.y);
      float w2 = __int_as_float(r2.y), w3 = __int_as_float(r3.y);
      a0 += w0 * bf2f(v0 & 0xffffu); a1 += w0 * bf2f(v0 >> 16);
      b0 += w1 * bf2f(v1 & 0xffffu); b1 += w1 * bf2f(v1 >> 16);
      c0a += w2 * bf2f(v2 & 0xffffu); c1a += w2 * bf2f(v2 >> 16);
      d0 += w3 * bf2f(v3 & 0xffffu); d1 += w3 * bf2f(v3 >> 16);
    }
    for (; e < s1; ++e) {
      int2 r = er[e];
      float w = __int_as_float(r.y);
      unsigned v = *(const unsigned*)(ga2b + (size_t)r.x * 208 + c0);
      a0 += w * bf2f(v & 0xffffu); a1 += w * bf2f(v >> 16);
    }
    float dd = -dinv[wid];
    float p0 = dd * ((a0 + b0) + (c0a + d0));
    float p1 = dd * ((a1 + b1) + (c1a + d1));
    unsigned av = *(const unsigned*)(ga2b + (size_t)wid * 208 + 104 + c0);
    float h0 = fmaxf(bf2f(av & 0xffffu) + p0 + b2[c0], 0.f);
    float h1 = fmaxf(bf2f(av >> 16) + p1 + b2[c0 + 1], 0.f);
    aa = h0 * W30[c0] + h1 * W30[c0 + 1];
    gg = h0 * W31[c0] + h1 * W31[c0 + 1];
  }
#pragma unroll
  for (int off = 32; off > 0; off >>= 1) {
    aa += __shfl_xor(aa, off);
    gg += __shfl_xor(gg, off);
  }
  if (lane == 0) {
    a3[wid] = aa + b3[0];
    g3[wid] = gg;
  }
}

__global__ void k_gather1(const unsigned* __restrict__ rowstart, const int2* __restrict__ er,
                          const float* __restrict__ dinv, const float* __restrict__ g3,
                          const float* __restrict__ a3, float* __restrict__ out, int N) {
  int n = blockIdx.x * blockDim.x + threadIdx.x;
  if (n >= N) return;
  unsigned s0 = rowstart[n], s1 = rowstart[n + 1];
  float a = 0.f, b = 0.f, c = 0.f, d = 0.f;
  unsigned e = s0;
  for (; e + 4 <= s1; e += 4) {
    int2 r0 = er[e], r1 = er[e + 1], r2 = er[e + 2], r3 = er[e + 3];
    float g0 = g3[r0.x], g1 = g3[r1.x], g2v = g3[r2.x], g3v = g3[r3.x];
    a += __int_as_float(r0.y) * g0;
    b += __int_as_float(r1.y) * g1;
    c += __int_as_float(r2.y) * g2v;
    d += __int_as_float(r3.y) * g3v;
  }
  for (; e < s1; ++e) {
    int2 r = er[e];
    a += __int_as_float(r.y) * g3[r.x];
  }
  out[n] = a3[n] - dinv[n] * ((a + b) + (c + d));
}

// ---------------- MFMA matmuls (swapped-operand, slab W, LDS epilogue) ------
// h1b = relu(xb @ W1 + b1) over 320 cols (300 real + 20 zero pad).
// Block: 4 waves x 16 nodes. s-loop: stage W slab (20KB memcpy), 2 barriers,
// 1 X-load + 20 ds_read + 20 mfma per wave. After s-loop the slab is dead:
// one barrier, reuse smem as per-wave out-stage [16][168] (pad breaks bank
// stride), copy 320B full-line row runs.
__global__ __launch_bounds__(256) void k_mm1_mfma(
    const unsigned short* __restrict__ xb, const uint4* __restrict__ W1f,
    const float* __restrict__ b1pad, unsigned short* __restrict__ h1b) {
  __shared__ char smem[21504];  // max(slab 20480, outstage 4*16*168*2)
  uint4* slab = (uint4*)smem;
  int tid = threadIdx.x;
  int lane = tid & 63, wv = tid >> 6, lr = lane & 15, g = lane >> 4;
  int n0 = blockIdx.x * 64 + wv * 16;
  f32x4 acc[20];
#pragma unroll
  for (int j = 0; j < 20; j++) acc[j] = (f32x4){0.f, 0.f, 0.f, 0.f};
#pragma unroll
  for (int s = 0; s < 4; s++) {
    uint4 st[5];
#pragma unroll
    for (int q = 0; q < 5; q++) st[q] = W1f[s * 1280 + q * 256 + tid];
    __syncthreads();  // previous slab fully consumed
#pragma unroll
    for (int q = 0; q < 5; q++) slab[q * 256 + tid] = st[q];
    __syncthreads();  // new slab ready
    bf16x8 a = *(const bf16x8*)(xb + (size_t)(n0 + lr) * 128 + s * 32 + g * 8);
#pragma unroll
    for (int j = 0; j < 20; j++) {
      bf16x8 w = *(const bf16x8*)&slab[j * 64 + lane];
      acc[j] = __builtin_amdgcn_mfma_f32_16x16x32_bf16(w, a, acc[j], 0, 0, 0);
    }
  }
  __syncthreads();  // slab dead everywhere; smem becomes per-wave out-stage
  unsigned short* ost = (unsigned short*)smem + wv * 16 * 168;
  size_t gbase = (size_t)n0 * 320;
#pragma unroll
  for (int h = 0; h < 2; h++) {
#pragma unroll
    for (int jj = 0; jj < 10; jj++) {
      int j = h * 10 + jj;
      float4 bv = *(const float4*)(b1pad + j * 16 + g * 4);
      unsigned lo = f2bf(fmaxf(acc[j][0] + bv.x, 0.f)) |
                    (f2bf(fmaxf(acc[j][1] + bv.y, 0.f)) << 16);
      unsigned hi = f2bf(fmaxf(acc[j][2] + bv.z, 0.f)) |
                    (f2bf(fmaxf(acc[j][3] + bv.w, 0.f)) << 16);
      uint2 pk; pk.x = lo; pk.y = hi;
      *(uint2*)(ost + lr * 168 + jj * 16 + g * 4) = pk;
    }
    // wave-private stage -> global: 16 rows x 320B (5 full 64B lines each)
    for (int idx = lane; idx < 320; idx += 64) {
      int row = idx / 20, q = idx - row * 20;
      *(uint4*)(h1b + gbase + (size_t)row * 320 + h * 160 + q * 8) =
          *(const uint4*)(ost + row * 168 + q * 8);
    }
  }
}

// ga2b = h1b @ [W21|pad|W20|pad]. 13 col-tiles, K=320 (10 s-steps).
// Same structure; out-stage [16][216], wave tile = one contiguous 6656B span.
__global__ __launch_bounds__(256) void k_mm2_mfma(
    const unsigned short* __restrict__ h1b, const uint4* __restrict__ W2f,
    unsigned short* __restrict__ ga2b) {
  __shared__ char smem[27648];  // max(slab 13312, outstage 4*16*216*2)
  uint4* slab = (uint4*)smem;
  int tid = threadIdx.x;
  int lane = tid & 63, wv = tid >> 6, lr = lane & 15, g = lane >> 4;
  int n0 = blockIdx.x * 64 + wv * 16;
  f32x4 acc[13];
#pragma unroll
  for (int j = 0; j < 13; j++) acc[j] = (f32x4){0.f, 0.f, 0.f, 0.f};
#pragma unroll
  for (int s = 0; s < 10; s++) {
    uint4 st0 = W2f[s * 832 + tid];
    uint4 st1 = W2f[s * 832 + 256 + tid];
    uint4 st2 = W2f[s * 832 + 512 + tid];
    uint4 st3 = {0, 0, 0, 0};
    if (tid < 64) st3 = W2f[s * 832 + 768 + tid];
    __syncthreads();  // previous slab fully consumed
    slab[tid] = st0;
    slab[256 + tid] = st1;
    slab[512 + tid] = st2;
    if (tid < 64) slab[768 + tid] = st3;
    __syncthreads();  // new slab ready
    bf16x8 a = *(const bf16x8*)(h1b + (size_t)(n0 + lr) * 320 + s * 32 + g * 8);
#pragma unroll
    for (int j = 0; j < 13; j++) {
      bf16x8 w = *(const bf16x8*)&slab[j * 64 + lane];
      acc[j] = __builtin_amdgcn_mfma_f32_16x16x32_bf16(w, a, acc[j], 0, 0, 0);
    }
  }
  __syncthreads();  // slab dead; smem becomes per-wave out-stage
  unsigned short* ost = (unsigned short*)smem + wv * 16 * 216;
#pragma unroll
  for (int j = 0; j < 13; j++) {
    unsigned lo = f2bf(acc[j][0]) | (f2bf(acc[j][1]) << 16);
    unsigned hi = f2bf(acc[j][2]) | (f2bf(acc[j][3]) << 16);
    uint2 pk; pk.x = lo; pk.y = hi;
    *(uint2*)(ost + lr * 216 + j * 16 + g * 4) = pk;
  }
  // wave tile rows n0..n0+15 x 208 cols = 6656 contiguous bytes
  uint4* gdst = (uint4*)(ga2b + (size_t)n0 * 208);
  for (int idx = lane; idx < 416; idx += 64) {
    int row = idx / 26, q = idx - row * 26;
    gdst[idx] = *(const uint4*)(ost + row * 216 + q * 8);
  }
}

// ---------------- launch ----------------
extern "C" void kernel_launch(void* const* d_in, const int* in_sizes, int n_in,
                              void* d_out, int out_size, void* d_ws, size_t ws_size,
                              hipStream_t stream) {
  const float* x  = (const float*)d_in[0];
  const int*   ei = (const int*)d_in[1];
  const float* W1 = (const float*)d_in[2];  // [2][58][300]
  const float* b1 = (const float*)d_in[3];
  const float* W2 = (const float*)d_in[4];  // [2][300][100]
  const float* b2 = (const float*)d_in[5];
  const float* W3 = (const float*)d_in[6];  // [2][100][1]
  const float* b3 = (const float*)d_in[7];
  float* out = (float*)d_out;

  const int N = in_sizes[0] / 58;            // 100000
  const int E = in_sizes[1] / 2;             // 800000
  const int NR = (N + 127) & ~127;           // 100096 (multiple of 64)
  const int NB = (N + 1023) / 1024;
  const int* src = ei;
  const int* dst = ei + E;

  char* ws = (char*)d_ws;
  size_t off = 0;
  auto alloc = [&](size_t bytes) -> void* {
    void* p = ws + off;
    off += (bytes + 255) & ~(size_t)255;
    return p;
  };
  unsigned* deg      = (unsigned*)alloc((size_t)2 * N * 4);
  unsigned* cnt      = deg + N;
  float*    dinv     = (float*)alloc((size_t)N * 4);
  unsigned* rowstart = (unsigned*)alloc((size_t)(N + 1) * 4);
  unsigned* cursor   = (unsigned*)alloc((size_t)N * 4);
  unsigned* btot     = (unsigned*)alloc((size_t)256 * 4);
  int2*     er       = (int2*)alloc((size_t)E * 8);
  unsigned short* xb   = (unsigned short*)alloc((size_t)NR * 128 * 2);
  uint4*    W1f      = (uint4*)alloc((size_t)4 * 20 * 64 * 16);   // 80 KB
  uint4*    W2f      = (uint4*)alloc((size_t)10 * 13 * 64 * 16);  // 133 KB
  float*    b1pad    = (float*)alloc((size_t)320 * 4);
  unsigned short* h1b  = (unsigned short*)alloc((size_t)NR * 320 * 2);
  unsigned short* ga2b = (unsigned short*)alloc((size_t)NR * 208 * 2);
  float* a3 = (float*)alloc((size_t)N * 4);
  float* g3 = (float*)alloc((size_t)N * 4);

  // --- CSR + dinv ---
  hipMemsetAsync(deg, 0, (size_t)2 * N * 4, stream);
  k_count<<<(E + 255) / 256, 256, 0, stream>>>(src, dst, deg, cnt, E);
  k_dinv<<<(N + 255) / 256, 256, 0, stream>>>(deg, dinv, N);
  k_scan1<<<NB, 256, 0, stream>>>(cnt, btot, N);
  k_scan2<<<1, 256, 0, stream>>>(btot, rowstart, NB, N, E);
  k_scan3<<<NB, 256, 0, stream>>>(cnt, btot, rowstart, cursor, N);
  k_fill<<<(E + 255) / 256, 256, 0, stream>>>(src, dst, dinv, cursor, er, E);

  // --- preps ---
  k_prep_w1f<<<(4 * 20 * 64 + 255) / 256, 256, 0, stream>>>(W1, W1f);
  k_prep_w2f<<<(10 * 13 * 64 + 255) / 256, 256, 0, stream>>>(W2, W2f);
  k_prep_b1pad<<<2, 256, 0, stream>>>(b1, b1pad);
  k_prep_xb<<<((size_t)N * 64 + 255) / 256, 256, 0, stream>>>(x, xb, N);

  // --- layer 1 ---
  k_gather58<<<(N + 3) / 4, 256, 0, stream>>>(rowstart, er, dinv, xb, N);
  k_mm1_mfma<<<NR / 64, 256, 0, stream>>>(xb, W1f, b1pad, h1b);

  // --- layer 2 ---
  k_mm2_mfma<<<NR / 64, 256, 0, stream>>>(h1b, W2f, ga2b);
  k_gather_l2<<<(N + 3) / 4, 256, 0, stream>>>(rowstart, er, dinv, ga2b,
                                               b2, W3, W3 + 100, b3, a3, g3, N);

  // --- layer 3 ---
  k_gather1<<<(N + 255) / 256, 256, 0, stream>>>(rowstart, er, dinv, g3, a3, out, N);
}